// Round 4
// baseline (308.687 us; speedup 1.0000x reference)
//
#include <hip/hip_runtime.h>
#include <math.h>
#include <type_traits>

#define DIM 1024
#define NH 16
#define HD 64
#define BATCH 4
#define SEQ 2048
#define EPS 1e-6f

typedef __attribute__((ext_vector_type(8))) short short8;
typedef __attribute__((ext_vector_type(4))) short short4v;
typedef __attribute__((ext_vector_type(4))) float float4v;

// f32 -> bf16 round-to-nearest-even (scalar)
__device__ inline unsigned short f2bf(float f) {
    unsigned u = __float_as_uint(f);
    u += 0x7FFF + ((u >> 16) & 1);
    return (unsigned short)(u >> 16);
}
__device__ inline float bf2f(unsigned short b) {
    return __uint_as_float(((unsigned)b) << 16);
}
// pack two f32 -> two bf16 (round-half-up): 2 adds + 1 perm  [proven]
__device__ inline unsigned pk2bf(float lo, float hi) {
    unsigned ul = __float_as_uint(lo) + 0x8000u;
    unsigned uh = __float_as_uint(hi) + 0x8000u;
    return __builtin_amdgcn_perm(uh, ul, 0x07060302u);
}

// [proven exp2 path]
#if __has_builtin(__builtin_amdgcn_exp2f)
#define EXP2F(x) __builtin_amdgcn_exp2f(x)
#else
#define EXP2F(x) exp2f(x)
#endif

// 16x16x16 bf16 MFMA
#if __has_builtin(__builtin_amdgcn_mfma_f32_16x16x16bf16_1k)
__device__ inline float4v mfma16(short4v a, short4v b, float4v c) {
    return __builtin_amdgcn_mfma_f32_16x16x16bf16_1k(a, b, c, 0, 0, 0);
}
#elif __has_builtin(__builtin_amdgcn_mfma_f32_16x16x16_bf16)
__device__ inline float4v mfma16(short4v a, short4v b, float4v c) {
    return __builtin_amdgcn_mfma_f32_16x16x16_bf16(a, b, c, 0, 0, 0);
}
#else
__device__ inline float4v mfma16(short4v a, short4v b, float4v c) {
    asm volatile("v_mfma_f32_16x16x16_bf16 %0, %1, %2, %0\n\ts_nop 4"
                 : "+v"(c) : "v"(a), "v"(b));
    return c;
}
#endif

#define GLDS16(gp, lp) __builtin_amdgcn_global_load_lds( \
    (const __attribute__((address_space(1))) void*)(gp), \
    (__attribute__((address_space(3))) void*)(lp), 16, 0, 0)

// ---------------------------------------------------------------------------
// prep: x cast | qkv_w cast (q/k rows permuted for in-register RoPE) |
// proj_w cast | packed cos/sin table   [identical to R6]
// ---------------------------------------------------------------------------
__global__ __launch_bounds__(256) void prep_all(
    const float* __restrict__ x, const float* __restrict__ qkv_w,
    const float* __restrict__ proj_w,
    const float* __restrict__ cos_t, const float* __restrict__ sin_t,
    unsigned short* __restrict__ xb, unsigned short* __restrict__ qkvwb,
    unsigned short* __restrict__ projwb, unsigned* __restrict__ csP)
{
    const int bid = blockIdx.x;
    if (bid < 8192) {
        int i = bid * 256 + threadIdx.x;
        float4 f = ((const float4*)x)[i];
        ushort4 o;
        o.x = f2bf(f.x); o.y = f2bf(f.y); o.z = f2bf(f.z); o.w = f2bf(f.w);
        ((ushort4*)xb)[i] = o;
    } else if (bid < 8192 + 3072) {
        const int rn = bid - 8192;
        int ro = rn;
        if (rn < 2048) {
            const int head = rn >> 6, c = rn & 63, j = c >> 4, cl = c & 15;
            ro = (head << 6) + ((j & 1) + 2 * cl + 32 * (j >> 1));
        }
        float4 f = ((const float4*)(qkv_w + (long)ro * DIM))[threadIdx.x];
        ushort4 o;
        o.x = f2bf(f.x); o.y = f2bf(f.y); o.z = f2bf(f.z); o.w = f2bf(f.w);
        ((ushort4*)(qkvwb + (long)rn * DIM))[threadIdx.x] = o;
    } else if (bid < 8192 + 3072 + 1024) {
        int i = (bid - 11264) * 256 + threadIdx.x;
        float4 f = ((const float4*)proj_w)[i];
        ushort4 o;
        o.x = f2bf(f.x); o.y = f2bf(f.y); o.z = f2bf(f.z); o.w = f2bf(f.w);
        ((ushort4*)projwb)[i] = o;
    } else {
        int i = (bid - 12288) * 256 + threadIdx.x;
        int a = i >> 11, s = i & 2047;
        float c = cos_t[s * 64 + 2 * a], sn = sin_t[s * 64 + 2 * a];
        csP[a * SEQ + s] = ((unsigned)f2bf(sn) << 16) | f2bf(c);
    }
}

// ---------------------------------------------------------------------------
// Fused QKV GEMM + bias + RMSNorm + RoPE + V fragment store  [identical to R6]
// ---------------------------------------------------------------------------
__global__ __launch_bounds__(256) void gemm_qkv_fused(
    const unsigned short* __restrict__ A, const unsigned short* __restrict__ W,
    const float* __restrict__ bias, const unsigned* __restrict__ csP,
    const float* __restrict__ qw, const float* __restrict__ kw,
    unsigned short* __restrict__ q, unsigned short* __restrict__ k,
    unsigned short* __restrict__ vt)
{
    __shared__ __align__(16) unsigned short As[128 * 32];
    __shared__ __align__(16) unsigned short Bs[128 * 32];

    const int t    = threadIdx.x;
    const int lane = t & 63;
    const int w    = t >> 6;
    const int row0 = blockIdx.y * 128;
    const int col0 = blockIdx.x * 128;
    const int wr   = (w & 1) * 64;
    const int wc   = (w >> 1) * 64;
    const int cl   = lane & 15;
    const int quad = lane >> 4;

    float4v acc[4][4];
#pragma unroll
    for (int i = 0; i < 4; ++i)
#pragma unroll
        for (int j = 0; j < 4; ++j) acc[i][j] = (float4v){0.f, 0.f, 0.f, 0.f};

    const int off1 = t * 16, off2 = 4096 + t * 16;
    const int r1 = off1 >> 6, c1 = off1 & 63;
    const int r2 = off2 >> 6, c2 = off2 & 63;
    const char* Ab = (const char*)A + (long)row0 * DIM * 2;
    const char* Wb = (const char*)W + (long)col0 * DIM * 2;
    const long  ks = DIM * 2;

    for (int k0 = 0; k0 < DIM; k0 += 32) {
        const long kb = (long)k0 * 2;
        GLDS16(Ab + (long)r1 * ks + kb + c1, (char*)As + off1);
        GLDS16(Ab + (long)r2 * ks + kb + c2, (char*)As + off2);
        GLDS16(Wb + (long)r1 * ks + kb + c1, (char*)Bs + off1);
        GLDS16(Wb + (long)r2 * ks + kb + c2, (char*)Bs + off2);
        __syncthreads();

        short8 af[4], bfr[4];
#pragma unroll
        for (int i = 0; i < 4; ++i)
            af[i] = *(const short8*)&As[(wr + i * 16 + cl) * 32 + quad * 8];
#pragma unroll
        for (int j = 0; j < 4; ++j)
            bfr[j] = *(const short8*)&Bs[(wc + j * 16 + cl) * 32 + quad * 8];
#pragma unroll
        for (int i = 0; i < 4; ++i)
#pragma unroll
            for (int j = 0; j < 4; ++j)
                acc[i][j] = __builtin_amdgcn_mfma_f32_16x16x32_bf16(af[i], bfr[j], acc[i][j], 0, 0, 0);
        __syncthreads();
    }

    const int gcol  = col0 + wc;
    const int b     = row0 >> 11;
    const int srow0 = (row0 & 2047) + wr;

    if (gcol < 2 * DIM) {
        const bool isq = (gcol < DIM);
        const int  h   = (isq ? gcol : gcol - DIM) >> 6;
        const float* nw = isq ? qw : kw;
        const float scale = isq ? 0.180336880f : 1.0f;   // 0.125*log2(e)
        unsigned short* dst = (isq ? q : k) + (long)(b * NH + h) * SEQ * 64;

        float bjv[4];
#pragma unroll
        for (int j = 0; j < 4; ++j)
            bjv[j] = bias[gcol + (j & 1) + 2 * cl + 32 * (j >> 1)];
#pragma unroll
        for (int i = 0; i < 4; ++i)
#pragma unroll
            for (int j = 0; j < 4; ++j)
#pragma unroll
                for (int r = 0; r < 4; ++r) acc[i][j][r] += bjv[j];

        float rinv[4][4];
#pragma unroll
        for (int i = 0; i < 4; ++i)
#pragma unroll
            for (int r = 0; r < 4; ++r) {
                float ss = acc[i][0][r] * acc[i][0][r];
                ss = fmaf(acc[i][1][r], acc[i][1][r], ss);
                ss = fmaf(acc[i][2][r], acc[i][2][r], ss);
                ss = fmaf(acc[i][3][r], acc[i][3][r], ss);
                ss += __shfl_xor(ss, 1, 64);
                ss += __shfl_xor(ss, 2, 64);
                ss += __shfl_xor(ss, 4, 64);
                ss += __shfl_xor(ss, 8, 64);
                rinv[i][r] = rsqrtf(ss * (1.f / 64.f) + EPS) * scale;
            }

        const float nwe[2] = { nw[2 * cl],     nw[32 + 2 * cl] };
        const float nwo[2] = { nw[2 * cl + 1], nw[33 + 2 * cl] };

#pragma unroll
        for (int i = 0; i < 4; ++i) {
            const int sb = srow0 + i * 16 + quad * 4;
#pragma unroll
            for (int jp = 0; jp < 2; ++jp) {
                uint4 cs4 = *(const uint4*)(csP + (long)(jp * 16 + cl) * SEQ + sb);
#pragma unroll
                for (int r = 0; r < 4; ++r) {
                    float g  = rinv[i][r];
                    float xe = acc[i][2 * jp][r]     * g * nwe[jp];
                    float xo = acc[i][2 * jp + 1][r] * g * nwo[jp];
                    unsigned u = (r == 0) ? cs4.x : (r == 1) ? cs4.y : (r == 2) ? cs4.z : cs4.w;
                    float c  = bf2f((unsigned short)(u & 0xffff));
                    float sn = bf2f((unsigned short)(u >> 16));
                    float oe = fmaf(xe, c, -(xo * sn));
                    float oo = fmaf(xo, c,   xe * sn);
                    *(unsigned*)(dst + (long)(sb + r) * 64 + jp * 32 + 2 * cl) = pk2bf(oe, oo);
                }
            }
        }
    } else {
        const int h = (gcol - 2 * DIM) >> 6;
        float bjv[4];
#pragma unroll
        for (int j = 0; j < 4; ++j) bjv[j] = bias[gcol + j * 16 + cl];
        unsigned short* vdst = vt + (long)(b * NH + h) * SEQ * 64
                                  + (long)(srow0 >> 6) * 4096;
#pragma unroll
        for (int j = 0; j < 4; ++j)
#pragma unroll
            for (int ip = 0; ip < 2; ++ip) {
                const int i0 = 2 * ip;
                uint4 st;
                st.x = pk2bf(acc[i0][j][0] + bjv[j],     acc[i0][j][1] + bjv[j]);
                st.y = pk2bf(acc[i0][j][2] + bjv[j],     acc[i0][j][3] + bjv[j]);
                st.z = pk2bf(acc[i0 + 1][j][0] + bjv[j], acc[i0 + 1][j][1] + bjv[j]);
                st.w = pk2bf(acc[i0 + 1][j][2] + bjv[j], acc[i0 + 1][j][3] + bjv[j]);
                *(uint4*)(vdst + (j * 2 + ip) * 512 + lane * 8) = st;
            }
    }
}

// ---------------------------------------------------------------------------
// proj GEMM  [identical to R6]
// ---------------------------------------------------------------------------
__global__ __launch_bounds__(256) void gemm_proj(
    const unsigned short* __restrict__ A, const unsigned short* __restrict__ W,
    const float* __restrict__ bias, float* __restrict__ C)
{
    __shared__ __align__(16) unsigned short As[128 * 32];
    __shared__ __align__(16) unsigned short Bs[128 * 32];

    const int t    = threadIdx.x;
    const int lane = t & 63;
    const int w    = t >> 6;
    const int row0 = blockIdx.y * 128;
    const int col0 = blockIdx.x * 128;
    const int wr   = (w & 1) * 64;
    const int wc   = (w >> 1) * 64;

    float4v acc[4][4];
#pragma unroll
    for (int i = 0; i < 4; ++i)
#pragma unroll
        for (int j = 0; j < 4; ++j) acc[i][j] = (float4v){0.f, 0.f, 0.f, 0.f};

    const int off1 = t * 16, off2 = 4096 + t * 16;
    const int r1 = off1 >> 6, c1 = off1 & 63;
    const int r2 = off2 >> 6, c2 = off2 & 63;
    const char* Ab = (const char*)A + (long)row0 * DIM * 2;
    const char* Wb = (const char*)W + (long)col0 * DIM * 2;
    const long  ks = DIM * 2;

    for (int k0 = 0; k0 < DIM; k0 += 32) {
        const long kb = (long)k0 * 2;
        GLDS16(Ab + (long)r1 * ks + kb + c1, (char*)As + off1);
        GLDS16(Ab + (long)r2 * ks + kb + c2, (char*)As + off2);
        GLDS16(Wb + (long)r1 * ks + kb + c1, (char*)Bs + off1);
        GLDS16(Wb + (long)r2 * ks + kb + c2, (char*)Bs + off2);
        __syncthreads();

        short8 af[4], bfr[4];
#pragma unroll
        for (int i = 0; i < 4; ++i)
            af[i] = *(const short8*)&As[(wr + i * 16 + (lane & 15)) * 32 + (lane >> 4) * 8];
#pragma unroll
        for (int j = 0; j < 4; ++j)
            bfr[j] = *(const short8*)&Bs[(wc + j * 16 + (lane & 15)) * 32 + (lane >> 4) * 8];
#pragma unroll
        for (int i = 0; i < 4; ++i)
#pragma unroll
            for (int j = 0; j < 4; ++j)
                acc[i][j] = __builtin_amdgcn_mfma_f32_16x16x32_bf16(af[i], bfr[j], acc[i][j], 0, 0, 0);
        __syncthreads();
    }

    const int qd = lane >> 4, cl = lane & 15;
#pragma unroll
    for (int j = 0; j < 4; ++j) {
        const int col = col0 + wc + j * 16 + cl;
        const float bj = bias[col];
#pragma unroll
        for (int i = 0; i < 4; ++i) {
            const long rr = row0 + wr + i * 16 + qd * 4;
#pragma unroll
            for (int r = 0; r < 4; ++r)
                C[(rr + r) * (long)DIM + col] = acc[i][j][r] + bj;
        }
    }
}

// ---------------------------------------------------------------------------
// MFMA flash attention. Proven 2-barrier schedule + proven swizzle (R3:
// conflicts 4.19M -> 0). ONE change vs R3: KV tile 64 -> 128 rows. Staging
// bytes, VALU, and MFMA totals are unchanged, but the number of
// stage->drain->barrier events halves (32 -> 16 per block), amortizing the
// exposed L2-latency drain that R3 showed dominates (MfmaUtil 48% with
// conflicts at 0). Compute body = the existing proven 64-row body run twice
// per barrier pair (register pressure unchanged). Swizzle algebra invariant:
// row offsets 64·s keep (row>>1)&3 and scbS unchanged (64>>1 = 32 ≡ 0 mod 4).
// LDS 16 -> 32 KB (still 4 blocks/CU; cap is 5).
// ---------------------------------------------------------------------------
__global__ __launch_bounds__(256) void flash_mfma(
    const unsigned short* __restrict__ q, const unsigned short* __restrict__ k,
    const unsigned short* __restrict__ vt, unsigned short* __restrict__ out)
{
    __shared__ __align__(16) unsigned short Ks[2][128 * 32];
    __shared__ __align__(16) unsigned short Vts[128 * 64];

    const int t    = threadIdx.x;
    const int lane = t & 63;
    const int w    = t >> 6;
    const int bh   = blockIdx.y;
    const int b    = bh >> 4;
    const int h    = bh & 15;
    const int q0   = blockIdx.x * 128;
    const int cl   = lane & 15;
    const int quad = lane >> 4;
    // swizzled 16B slot for K reads: row = s*64 + j*16 + cl, (row>>1)&3 == (cl>>1)&3
    const int qs   = quad ^ ((cl >> 1) & 3);

    const char* qb  = (const char*)(q  + (long)bh * SEQ * 64);
    const char* kb  = (const char*)(k  + (long)bh * SEQ * 64);
    const char* vtb = (const char*)(vt + (long)bh * SEQ * 64);

    // Q fragments straight to registers (read once, outside the loop)
    short8 aq[2][2];
#pragma unroll
    for (int qg = 0; qg < 2; ++qg)
#pragma unroll
        for (int hf = 0; hf < 2; ++hf)
            aq[qg][hf] = *(const short8*)(qb +
                (long)(q0 + w * 32 + qg * 16 + cl) * 128 + hf * 64 + quad * 16);

    const short4v ones = (short4v){(short)0x3F80, (short)0x3F80,
                                   (short)0x3F80, (short)0x3F80};

    float4v o[2][4], o4[2];
#pragma unroll
    for (int qg = 0; qg < 2; ++qg) {
        o4[qg] = (float4v){0.f, 0.f, 0.f, 0.f};
#pragma unroll
        for (int i = 0; i < 4; ++i) o[qg][i] = (float4v){0.f, 0.f, 0.f, 0.f};
    }

    const int soff = t * 16, srow = soff >> 6;
    // source column pre-swizzled with the SAME involution the read applies:
    // LDS(row, c) = G(row, c ^ f(row)),  f(row) = ((row>>1)&3)<<4
    // (invariant under row += 64, so one scbS serves both staging passes)
    const int scbS = (soff & 63) ^ (((srow >> 1) & 3) << 4);

    for (int kt = 0; kt < SEQ / 128; ++kt) {
        // K: 128 rows x 128 B, split into two 64-byte halves x two 64-row passes
#pragma unroll
        for (int p = 0; p < 2; ++p) {
            const long grow = (long)(kt * 128 + p * 64 + srow) * 128;
            GLDS16(kb + grow + scbS,      (char*)Ks[0] + p * 4096 + soff);
            GLDS16(kb + grow + 64 + scbS, (char*)Ks[1] + p * 4096 + soff);
        }
        // V: 128 rows x 128 B of fragments = 16 KB, four 4 KB passes
#pragma unroll
        for (int p = 0; p < 4; ++p)
            GLDS16(vtb + (long)kt * 16384 + p * 4096 + t * 16,
                   (char*)Vts + p * 4096 + t * 16);
        __syncthreads();

#pragma unroll
        for (int s = 0; s < 2; ++s) {
            short4v pa[2][4];
#pragma unroll
            for (int j = 0; j < 4; ++j) {
                short8 a0 = *(const short8*)&Ks[0][(s * 64 + j * 16 + cl) * 32 + qs * 8];
                short8 a1 = *(const short8*)&Ks[1][(s * 64 + j * 16 + cl) * 32 + qs * 8];
#pragma unroll
                for (int qg = 0; qg < 2; ++qg) {
                    float4v z = (float4v){0.f, 0.f, 0.f, 0.f};
                    z = __builtin_amdgcn_mfma_f32_16x16x32_bf16(a0, aq[qg][0], z, 0, 0, 0);
                    float4v sv = __builtin_amdgcn_mfma_f32_16x16x32_bf16(a1, aq[qg][1], z, 0, 0, 0);
                    float p0 = EXP2F(sv[0]), p1 = EXP2F(sv[1]);
                    float p2 = EXP2F(sv[2]), p3 = EXP2F(sv[3]);
                    unsigned lo = pk2bf(p0, p1), hi = pk2bf(p2, p3);
                    pa[qg][j] = __builtin_bit_cast(short4v, ((unsigned long long)hi << 32) | lo);
                    o4[qg] = mfma16(ones, pa[qg][j], o4[qg]);   // row sums on MFMA pipe
                }
            }

            // O^T += V^T @ P^T (V fragments shared across both q-groups)
#pragma unroll
            for (int fi = 0; fi < 4; ++fi) {
#pragma unroll
                for (int fjp = 0; fjp < 2; ++fjp) {
                    short8 vv = *(const short8*)&Vts[s * 4096 + (fi * 2 + fjp) * 512 + lane * 8];
                    short4v va = __builtin_shufflevector(vv, vv, 0, 1, 2, 3);
                    short4v vb = __builtin_shufflevector(vv, vv, 4, 5, 6, 7);
#pragma unroll
                    for (int qg = 0; qg < 2; ++qg) {
                        o[qg][fi] = mfma16(va, pa[qg][2 * fjp],     o[qg][fi]);
                        o[qg][fi] = mfma16(vb, pa[qg][2 * fjp + 1], o[qg][fi]);
                    }
                }
            }
        }
        __syncthreads();
    }

#pragma unroll
    for (int qg = 0; qg < 2; ++qg) {
        const float inv = 1.f / o4[qg][0];
        unsigned short* orow = out + ((long)b * SEQ + q0 + w * 32 + qg * 16 + cl) * DIM + h * 64;
#pragma unroll
        for (int i = 0; i < 4; ++i) {
            unsigned lo = pk2bf(o[qg][i][0] * inv, o[qg][i][1] * inv);
            unsigned hi = pk2bf(o[qg][i][2] * inv, o[qg][i][3] * inv);
            ushort4 st = __builtin_bit_cast(ushort4, ((unsigned long long)hi << 32) | lo);
            *(ushort4*)(orow + i * 16 + quad * 4) = st;
        }
    }
}

// ---------------------------------------------------------------------------
extern "C" void kernel_launch(void* const* d_in, const int* in_sizes, int n_in,
                              void* d_out, int out_size, void* d_ws, size_t ws_size,
                              hipStream_t stream)
{
    const float* x        = (const float*)d_in[0];
    const float* rope_cos = (const float*)d_in[1];
    const float* rope_sin = (const float*)d_in[2];
    const float* qkv_w    = (const float*)d_in[3];
    const float* qkv_b    = (const float*)d_in[4];
    const float* proj_w   = (const float*)d_in[5];
    const float* proj_b   = (const float*)d_in[6];
    const float* q_norm_w = (const float*)d_in[7];
    const float* k_norm_w = (const float*)d_in[8];
    float* outp = (float*)d_out;

    const int M = BATCH * SEQ;
    char* p = (char*)d_ws;
    unsigned short* xb    = (unsigned short*)p; p += (long)M * DIM * 2;
    unsigned short* qkvwb = (unsigned short*)p; p += (long)3 * DIM * DIM * 2;
    unsigned short* projwb= (unsigned short*)p; p += (long)DIM * DIM * 2;
    unsigned short* qb    = (unsigned short*)p; p += (long)M * DIM * 2;
    unsigned short* kbuf  = (unsigned short*)p; p += (long)M * DIM * 2;
    unsigned short* vtb   = (unsigned short*)p; p += (long)M * DIM * 2;
    unsigned short* attno = (unsigned short*)p; p += (long)M * DIM * 2;
    unsigned*       csP   = (unsigned*)p;       p += (long)32 * SEQ * 4;

    prep_all<<<dim3(12544), 256, 0, stream>>>(
        x, qkv_w, proj_w, rope_cos, rope_sin, xb, qkvwb, projwb, csP);

    gemm_qkv_fused<<<dim3(3 * DIM / 128, M / 128), 256, 0, stream>>>(
        xb, qkvwb, qkv_b, csP, q_norm_w, k_norm_w, qb, kbuf, vtb);

    flash_mfma<<<dim3(SEQ / 128, BATCH * NH), 256, 0, stream>>>(qb, kbuf, vtb, attno);

    gemm_proj<<<dim3(DIM / 128, M / 128), 256, 0, stream>>>(
        attno, projwb, proj_b, outp);
}

// Round 5
// 300.743 us; speedup vs baseline: 1.0264x; 1.0264x over previous
//
#include <hip/hip_runtime.h>
#include <math.h>
#include <type_traits>

#define DIM 1024
#define NH 16
#define HD 64
#define BATCH 4
#define SEQ 2048
#define EPS 1e-6f

typedef __attribute__((ext_vector_type(8))) short short8;
typedef __attribute__((ext_vector_type(4))) short short4v;
typedef __attribute__((ext_vector_type(4))) float float4v;

// f32 -> bf16 round-to-nearest-even (scalar)
__device__ inline unsigned short f2bf(float f) {
    unsigned u = __float_as_uint(f);
    u += 0x7FFF + ((u >> 16) & 1);
    return (unsigned short)(u >> 16);
}
__device__ inline float bf2f(unsigned short b) {
    return __uint_as_float(((unsigned)b) << 16);
}
// pack two f32 -> two bf16 (round-half-up): 2 adds + 1 perm  [proven]
__device__ inline unsigned pk2bf(float lo, float hi) {
    unsigned ul = __float_as_uint(lo) + 0x8000u;
    unsigned uh = __float_as_uint(hi) + 0x8000u;
    return __builtin_amdgcn_perm(uh, ul, 0x07060302u);
}

// [proven exp2 path]
#if __has_builtin(__builtin_amdgcn_exp2f)
#define EXP2F(x) __builtin_amdgcn_exp2f(x)
#else
#define EXP2F(x) exp2f(x)
#endif

// 16x16x16 bf16 MFMA
#if __has_builtin(__builtin_amdgcn_mfma_f32_16x16x16bf16_1k)
__device__ inline float4v mfma16(short4v a, short4v b, float4v c) {
    return __builtin_amdgcn_mfma_f32_16x16x16bf16_1k(a, b, c, 0, 0, 0);
}
#elif __has_builtin(__builtin_amdgcn_mfma_f32_16x16x16_bf16)
__device__ inline float4v mfma16(short4v a, short4v b, float4v c) {
    return __builtin_amdgcn_mfma_f32_16x16x16_bf16(a, b, c, 0, 0, 0);
}
#else
__device__ inline float4v mfma16(short4v a, short4v b, float4v c) {
    asm volatile("v_mfma_f32_16x16x16_bf16 %0, %1, %2, %0\n\ts_nop 4"
                 : "+v"(c) : "v"(a), "v"(b));
    return c;
}
#endif

#define GLDS16(gp, lp) __builtin_amdgcn_global_load_lds( \
    (const __attribute__((address_space(1))) void*)(gp), \
    (__attribute__((address_space(3))) void*)(lp), 16, 0, 0)

// ---------------------------------------------------------------------------
// prep: x cast | qkv_w cast (q/k rows permuted for in-register RoPE) |
// proj_w cast | packed cos/sin table   [identical to R6]
// ---------------------------------------------------------------------------
__global__ __launch_bounds__(256) void prep_all(
    const float* __restrict__ x, const float* __restrict__ qkv_w,
    const float* __restrict__ proj_w,
    const float* __restrict__ cos_t, const float* __restrict__ sin_t,
    unsigned short* __restrict__ xb, unsigned short* __restrict__ qkvwb,
    unsigned short* __restrict__ projwb, unsigned* __restrict__ csP)
{
    const int bid = blockIdx.x;
    if (bid < 8192) {
        int i = bid * 256 + threadIdx.x;
        float4 f = ((const float4*)x)[i];
        ushort4 o;
        o.x = f2bf(f.x); o.y = f2bf(f.y); o.z = f2bf(f.z); o.w = f2bf(f.w);
        ((ushort4*)xb)[i] = o;
    } else if (bid < 8192 + 3072) {
        const int rn = bid - 8192;
        int ro = rn;
        if (rn < 2048) {
            const int head = rn >> 6, c = rn & 63, j = c >> 4, cl = c & 15;
            ro = (head << 6) + ((j & 1) + 2 * cl + 32 * (j >> 1));
        }
        float4 f = ((const float4*)(qkv_w + (long)ro * DIM))[threadIdx.x];
        ushort4 o;
        o.x = f2bf(f.x); o.y = f2bf(f.y); o.z = f2bf(f.z); o.w = f2bf(f.w);
        ((ushort4*)(qkvwb + (long)rn * DIM))[threadIdx.x] = o;
    } else if (bid < 8192 + 3072 + 1024) {
        int i = (bid - 11264) * 256 + threadIdx.x;
        float4 f = ((const float4*)proj_w)[i];
        ushort4 o;
        o.x = f2bf(f.x); o.y = f2bf(f.y); o.z = f2bf(f.z); o.w = f2bf(f.w);
        ((ushort4*)projwb)[i] = o;
    } else {
        int i = (bid - 12288) * 256 + threadIdx.x;
        int a = i >> 11, s = i & 2047;
        float c = cos_t[s * 64 + 2 * a], sn = sin_t[s * 64 + 2 * a];
        csP[a * SEQ + s] = ((unsigned)f2bf(sn) << 16) | f2bf(c);
    }
}

// ---------------------------------------------------------------------------
// Fused QKV GEMM + bias + RMSNorm + RoPE + V fragment store  [identical to R6]
// ---------------------------------------------------------------------------
__global__ __launch_bounds__(256) void gemm_qkv_fused(
    const unsigned short* __restrict__ A, const unsigned short* __restrict__ W,
    const float* __restrict__ bias, const unsigned* __restrict__ csP,
    const float* __restrict__ qw, const float* __restrict__ kw,
    unsigned short* __restrict__ q, unsigned short* __restrict__ k,
    unsigned short* __restrict__ vt)
{
    __shared__ __align__(16) unsigned short As[128 * 32];
    __shared__ __align__(16) unsigned short Bs[128 * 32];

    const int t    = threadIdx.x;
    const int lane = t & 63;
    const int w    = t >> 6;
    const int row0 = blockIdx.y * 128;
    const int col0 = blockIdx.x * 128;
    const int wr   = (w & 1) * 64;
    const int wc   = (w >> 1) * 64;
    const int cl   = lane & 15;
    const int quad = lane >> 4;

    float4v acc[4][4];
#pragma unroll
    for (int i = 0; i < 4; ++i)
#pragma unroll
        for (int j = 0; j < 4; ++j) acc[i][j] = (float4v){0.f, 0.f, 0.f, 0.f};

    const int off1 = t * 16, off2 = 4096 + t * 16;
    const int r1 = off1 >> 6, c1 = off1 & 63;
    const int r2 = off2 >> 6, c2 = off2 & 63;
    const char* Ab = (const char*)A + (long)row0 * DIM * 2;
    const char* Wb = (const char*)W + (long)col0 * DIM * 2;
    const long  ks = DIM * 2;

    for (int k0 = 0; k0 < DIM; k0 += 32) {
        const long kb = (long)k0 * 2;
        GLDS16(Ab + (long)r1 * ks + kb + c1, (char*)As + off1);
        GLDS16(Ab + (long)r2 * ks + kb + c2, (char*)As + off2);
        GLDS16(Wb + (long)r1 * ks + kb + c1, (char*)Bs + off1);
        GLDS16(Wb + (long)r2 * ks + kb + c2, (char*)Bs + off2);
        __syncthreads();

        short8 af[4], bfr[4];
#pragma unroll
        for (int i = 0; i < 4; ++i)
            af[i] = *(const short8*)&As[(wr + i * 16 + cl) * 32 + quad * 8];
#pragma unroll
        for (int j = 0; j < 4; ++j)
            bfr[j] = *(const short8*)&Bs[(wc + j * 16 + cl) * 32 + quad * 8];
#pragma unroll
        for (int i = 0; i < 4; ++i)
#pragma unroll
            for (int j = 0; j < 4; ++j)
                acc[i][j] = __builtin_amdgcn_mfma_f32_16x16x32_bf16(af[i], bfr[j], acc[i][j], 0, 0, 0);
        __syncthreads();
    }

    const int gcol  = col0 + wc;
    const int b     = row0 >> 11;
    const int srow0 = (row0 & 2047) + wr;

    if (gcol < 2 * DIM) {
        const bool isq = (gcol < DIM);
        const int  h   = (isq ? gcol : gcol - DIM) >> 6;
        const float* nw = isq ? qw : kw;
        const float scale = isq ? 0.180336880f : 1.0f;   // 0.125*log2(e)
        unsigned short* dst = (isq ? q : k) + (long)(b * NH + h) * SEQ * 64;

        float bjv[4];
#pragma unroll
        for (int j = 0; j < 4; ++j)
            bjv[j] = bias[gcol + (j & 1) + 2 * cl + 32 * (j >> 1)];
#pragma unroll
        for (int i = 0; i < 4; ++i)
#pragma unroll
            for (int j = 0; j < 4; ++j)
#pragma unroll
                for (int r = 0; r < 4; ++r) acc[i][j][r] += bjv[j];

        float rinv[4][4];
#pragma unroll
        for (int i = 0; i < 4; ++i)
#pragma unroll
            for (int r = 0; r < 4; ++r) {
                float ss = acc[i][0][r] * acc[i][0][r];
                ss = fmaf(acc[i][1][r], acc[i][1][r], ss);
                ss = fmaf(acc[i][2][r], acc[i][2][r], ss);
                ss = fmaf(acc[i][3][r], acc[i][3][r], ss);
                ss += __shfl_xor(ss, 1, 64);
                ss += __shfl_xor(ss, 2, 64);
                ss += __shfl_xor(ss, 4, 64);
                ss += __shfl_xor(ss, 8, 64);
                rinv[i][r] = rsqrtf(ss * (1.f / 64.f) + EPS) * scale;
            }

        const float nwe[2] = { nw[2 * cl],     nw[32 + 2 * cl] };
        const float nwo[2] = { nw[2 * cl + 1], nw[33 + 2 * cl] };

#pragma unroll
        for (int i = 0; i < 4; ++i) {
            const int sb = srow0 + i * 16 + quad * 4;
#pragma unroll
            for (int jp = 0; jp < 2; ++jp) {
                uint4 cs4 = *(const uint4*)(csP + (long)(jp * 16 + cl) * SEQ + sb);
#pragma unroll
                for (int r = 0; r < 4; ++r) {
                    float g  = rinv[i][r];
                    float xe = acc[i][2 * jp][r]     * g * nwe[jp];
                    float xo = acc[i][2 * jp + 1][r] * g * nwo[jp];
                    unsigned u = (r == 0) ? cs4.x : (r == 1) ? cs4.y : (r == 2) ? cs4.z : cs4.w;
                    float c  = bf2f((unsigned short)(u & 0xffff));
                    float sn = bf2f((unsigned short)(u >> 16));
                    float oe = fmaf(xe, c, -(xo * sn));
                    float oo = fmaf(xo, c,   xe * sn);
                    *(unsigned*)(dst + (long)(sb + r) * 64 + jp * 32 + 2 * cl) = pk2bf(oe, oo);
                }
            }
        }
    } else {
        const int h = (gcol - 2 * DIM) >> 6;
        float bjv[4];
#pragma unroll
        for (int j = 0; j < 4; ++j) bjv[j] = bias[gcol + j * 16 + cl];
        unsigned short* vdst = vt + (long)(b * NH + h) * SEQ * 64
                                  + (long)(srow0 >> 6) * 4096;
#pragma unroll
        for (int j = 0; j < 4; ++j)
#pragma unroll
            for (int ip = 0; ip < 2; ++ip) {
                const int i0 = 2 * ip;
                uint4 st;
                st.x = pk2bf(acc[i0][j][0] + bjv[j],     acc[i0][j][1] + bjv[j]);
                st.y = pk2bf(acc[i0][j][2] + bjv[j],     acc[i0][j][3] + bjv[j]);
                st.z = pk2bf(acc[i0 + 1][j][0] + bjv[j], acc[i0 + 1][j][1] + bjv[j]);
                st.w = pk2bf(acc[i0 + 1][j][2] + bjv[j], acc[i0 + 1][j][3] + bjv[j]);
                *(uint4*)(vdst + (j * 2 + ip) * 512 + lane * 8) = st;
            }
    }
}

// ---------------------------------------------------------------------------
// proj GEMM  [identical to R6]
// ---------------------------------------------------------------------------
__global__ __launch_bounds__(256) void gemm_proj(
    const unsigned short* __restrict__ A, const unsigned short* __restrict__ W,
    const float* __restrict__ bias, float* __restrict__ C)
{
    __shared__ __align__(16) unsigned short As[128 * 32];
    __shared__ __align__(16) unsigned short Bs[128 * 32];

    const int t    = threadIdx.x;
    const int lane = t & 63;
    const int w    = t >> 6;
    const int row0 = blockIdx.y * 128;
    const int col0 = blockIdx.x * 128;
    const int wr   = (w & 1) * 64;
    const int wc   = (w >> 1) * 64;

    float4v acc[4][4];
#pragma unroll
    for (int i = 0; i < 4; ++i)
#pragma unroll
        for (int j = 0; j < 4; ++j) acc[i][j] = (float4v){0.f, 0.f, 0.f, 0.f};

    const int off1 = t * 16, off2 = 4096 + t * 16;
    const int r1 = off1 >> 6, c1 = off1 & 63;
    const int r2 = off2 >> 6, c2 = off2 & 63;
    const char* Ab = (const char*)A + (long)row0 * DIM * 2;
    const char* Wb = (const char*)W + (long)col0 * DIM * 2;
    const long  ks = DIM * 2;

    for (int k0 = 0; k0 < DIM; k0 += 32) {
        const long kb = (long)k0 * 2;
        GLDS16(Ab + (long)r1 * ks + kb + c1, (char*)As + off1);
        GLDS16(Ab + (long)r2 * ks + kb + c2, (char*)As + off2);
        GLDS16(Wb + (long)r1 * ks + kb + c1, (char*)Bs + off1);
        GLDS16(Wb + (long)r2 * ks + kb + c2, (char*)Bs + off2);
        __syncthreads();

        short8 af[4], bfr[4];
#pragma unroll
        for (int i = 0; i < 4; ++i)
            af[i] = *(const short8*)&As[(wr + i * 16 + (lane & 15)) * 32 + (lane >> 4) * 8];
#pragma unroll
        for (int j = 0; j < 4; ++j)
            bfr[j] = *(const short8*)&Bs[(wc + j * 16 + (lane & 15)) * 32 + (lane >> 4) * 8];
#pragma unroll
        for (int i = 0; i < 4; ++i)
#pragma unroll
            for (int j = 0; j < 4; ++j)
                acc[i][j] = __builtin_amdgcn_mfma_f32_16x16x32_bf16(af[i], bfr[j], acc[i][j], 0, 0, 0);
        __syncthreads();
    }

    const int qd = lane >> 4, cl = lane & 15;
#pragma unroll
    for (int j = 0; j < 4; ++j) {
        const int col = col0 + wc + j * 16 + cl;
        const float bj = bias[col];
#pragma unroll
        for (int i = 0; i < 4; ++i) {
            const long rr = row0 + wr + i * 16 + qd * 4;
#pragma unroll
            for (int r = 0; r < 4; ++r)
                C[(rr + r) * (long)DIM + col] = acc[i][j][r] + bj;
        }
    }
}

// ---------------------------------------------------------------------------
// MFMA flash attention. R2-R4 established: the per-iteration cost is
// proportional to bytes drained at the barrier (R4: halving barrier EVENTS
// with same bytes = neutral; R3: conflicts->0 = neutral). ONE change vs R3:
// V fragments are read DIRECT global->register (they are stored in exact
// fragment order by gemm_qkv; all 4 waves read the same 8KB -> L1-resident),
// issued AFTER the K barrier so their latency hides under QK+softmax via
// counted vmcnt instead of being drained at the barrier. Drain bytes per
// iteration halve (16KB -> 8KB K-only). LDS 32KB -> 8KB. K staging +
// swizzle + 2-barrier schedule unchanged (proven). launch_bounds(256,4)
// pins VGPR <= 128 so 4 blocks/CU still co-reside.
// ---------------------------------------------------------------------------
__global__ __launch_bounds__(256, 4) void flash_mfma(
    const unsigned short* __restrict__ q, const unsigned short* __restrict__ k,
    const unsigned short* __restrict__ vt, unsigned short* __restrict__ out)
{
    __shared__ __align__(16) unsigned short Ks[2][64 * 32];

    const int t    = threadIdx.x;
    const int lane = t & 63;
    const int w    = t >> 6;
    const int bh   = blockIdx.y;
    const int b    = bh >> 4;
    const int h    = bh & 15;
    const int q0   = blockIdx.x * 128;
    const int cl   = lane & 15;
    const int quad = lane >> 4;
    // swizzled 16B slot for K reads: row = j*16+cl, (row>>1)&3 == (cl>>1)&3
    const int qs   = quad ^ ((cl >> 1) & 3);

    const char* qb  = (const char*)(q  + (long)bh * SEQ * 64);
    const char* kb  = (const char*)(k  + (long)bh * SEQ * 64);
    const char* vtb = (const char*)(vt + (long)bh * SEQ * 64);

    // Q fragments straight to registers (read once, outside the loop)
    short8 aq[2][2];
#pragma unroll
    for (int qg = 0; qg < 2; ++qg)
#pragma unroll
        for (int hf = 0; hf < 2; ++hf)
            aq[qg][hf] = *(const short8*)(qb +
                (long)(q0 + w * 32 + qg * 16 + cl) * 128 + hf * 64 + quad * 16);

    const short4v ones = (short4v){(short)0x3F80, (short)0x3F80,
                                   (short)0x3F80, (short)0x3F80};

    float4v o[2][4], o4[2];
#pragma unroll
    for (int qg = 0; qg < 2; ++qg) {
        o4[qg] = (float4v){0.f, 0.f, 0.f, 0.f};
#pragma unroll
        for (int i = 0; i < 4; ++i) o[qg][i] = (float4v){0.f, 0.f, 0.f, 0.f};
    }

    const int soff = t * 16, srow = soff >> 6;
    // source column pre-swizzled with the SAME involution the read applies:
    // LDS(row, c) = G(row, c ^ f(row)),  f(row) = ((row>>1)&3)<<4
    const int scbS = (soff & 63) ^ (((srow >> 1) & 3) << 4);

    for (int kt = 0; kt < SEQ / 64; ++kt) {
        GLDS16(kb + (long)(kt * 64 + srow) * 128 + scbS,      (char*)Ks[0] + soff);
        GLDS16(kb + (long)(kt * 64 + srow) * 128 + 64 + scbS, (char*)Ks[1] + soff);
        __syncthreads();   // drains K staging only (8 KB)

        // V fragments direct from global, issued here so arrival is covered
        // by the QK+softmax phase (counted vmcnt, not barrier drain)
        short8 vf[8];
#pragma unroll
        for (int m = 0; m < 8; ++m)
            vf[m] = *(const short8*)(vtb + (long)kt * 8192 + m * 1024 + lane * 16);

        short4v pa[2][4];
#pragma unroll
        for (int j = 0; j < 4; ++j) {
            short8 a0 = *(const short8*)&Ks[0][(j * 16 + cl) * 32 + qs * 8];
            short8 a1 = *(const short8*)&Ks[1][(j * 16 + cl) * 32 + qs * 8];
#pragma unroll
            for (int qg = 0; qg < 2; ++qg) {
                float4v z = (float4v){0.f, 0.f, 0.f, 0.f};
                z = __builtin_amdgcn_mfma_f32_16x16x32_bf16(a0, aq[qg][0], z, 0, 0, 0);
                float4v s = __builtin_amdgcn_mfma_f32_16x16x32_bf16(a1, aq[qg][1], z, 0, 0, 0);
                float p0 = EXP2F(s[0]), p1 = EXP2F(s[1]);
                float p2 = EXP2F(s[2]), p3 = EXP2F(s[3]);
                unsigned lo = pk2bf(p0, p1), hi = pk2bf(p2, p3);
                pa[qg][j] = __builtin_bit_cast(short4v, ((unsigned long long)hi << 32) | lo);
                o4[qg] = mfma16(ones, pa[qg][j], o4[qg]);   // row sums on MFMA pipe
            }
        }

        // O^T += V^T @ P^T (V fragments in registers, shared across q-groups)
#pragma unroll
        for (int fi = 0; fi < 4; ++fi) {
#pragma unroll
            for (int fjp = 0; fjp < 2; ++fjp) {
                short8 vv = vf[fi * 2 + fjp];
                short4v va = __builtin_shufflevector(vv, vv, 0, 1, 2, 3);
                short4v vb = __builtin_shufflevector(vv, vv, 4, 5, 6, 7);
#pragma unroll
                for (int qg = 0; qg < 2; ++qg) {
                    o[qg][fi] = mfma16(va, pa[qg][2 * fjp],     o[qg][fi]);
                    o[qg][fi] = mfma16(vb, pa[qg][2 * fjp + 1], o[qg][fi]);
                }
            }
        }
        __syncthreads();   // protect Ks from next iteration's staging
    }

#pragma unroll
    for (int qg = 0; qg < 2; ++qg) {
        const float inv = 1.f / o4[qg][0];
        unsigned short* orow = out + ((long)b * SEQ + q0 + w * 32 + qg * 16 + cl) * DIM + h * 64;
#pragma unroll
        for (int i = 0; i < 4; ++i) {
            unsigned lo = pk2bf(o[qg][i][0] * inv, o[qg][i][1] * inv);
            unsigned hi = pk2bf(o[qg][i][2] * inv, o[qg][i][3] * inv);
            ushort4 st = __builtin_bit_cast(ushort4, ((unsigned long long)hi << 32) | lo);
            *(ushort4*)(orow + i * 16 + quad * 4) = st;
        }
    }
}

// ---------------------------------------------------------------------------
extern "C" void kernel_launch(void* const* d_in, const int* in_sizes, int n_in,
                              void* d_out, int out_size, void* d_ws, size_t ws_size,
                              hipStream_t stream)
{
    const float* x        = (const float*)d_in[0];
    const float* rope_cos = (const float*)d_in[1];
    const float* rope_sin = (const float*)d_in[2];
    const float* qkv_w    = (const float*)d_in[3];
    const float* qkv_b    = (const float*)d_in[4];
    const float* proj_w   = (const float*)d_in[5];
    const float* proj_b   = (const float*)d_in[6];
    const float* q_norm_w = (const float*)d_in[7];
    const float* k_norm_w = (const float*)d_in[8];
    float* outp = (float*)d_out;

    const int M = BATCH * SEQ;
    char* p = (char*)d_ws;
    unsigned short* xb    = (unsigned short*)p; p += (long)M * DIM * 2;
    unsigned short* qkvwb = (unsigned short*)p; p += (long)3 * DIM * DIM * 2;
    unsigned short* projwb= (unsigned short*)p; p += (long)DIM * DIM * 2;
    unsigned short* qb    = (unsigned short*)p; p += (long)M * DIM * 2;
    unsigned short* kbuf  = (unsigned short*)p; p += (long)M * DIM * 2;
    unsigned short* vtb   = (unsigned short*)p; p += (long)M * DIM * 2;
    unsigned short* attno = (unsigned short*)p; p += (long)M * DIM * 2;
    unsigned*       csP   = (unsigned*)p;       p += (long)32 * SEQ * 4;

    prep_all<<<dim3(12544), 256, 0, stream>>>(
        x, qkv_w, proj_w, rope_cos, rope_sin, xb, qkvwb, projwb, csP);

    gemm_qkv_fused<<<dim3(3 * DIM / 128, M / 128), 256, 0, stream>>>(
        xb, qkvwb, qkv_b, csP, q_norm_w, k_norm_w, qb, kbuf, vtb);

    flash_mfma<<<dim3(SEQ / 128, BATCH * NH), 256, 0, stream>>>(qb, kbuf, vtb, attno);

    gemm_proj<<<dim3(DIM / 128, M / 128), 256, 0, stream>>>(
        attno, projwb, proj_b, outp);
}

// Round 6
// 299.093 us; speedup vs baseline: 1.0321x; 1.0055x over previous
//
#include <hip/hip_runtime.h>
#include <math.h>
#include <type_traits>

#define DIM 1024
#define NH 16
#define HD 64
#define BATCH 4
#define SEQ 2048
#define EPS 1e-6f

typedef __attribute__((ext_vector_type(8))) short short8;
typedef __attribute__((ext_vector_type(4))) short short4v;
typedef __attribute__((ext_vector_type(4))) float float4v;

// f32 -> bf16 round-to-nearest-even (scalar)
__device__ inline unsigned short f2bf(float f) {
    unsigned u = __float_as_uint(f);
    u += 0x7FFF + ((u >> 16) & 1);
    return (unsigned short)(u >> 16);
}
__device__ inline float bf2f(unsigned short b) {
    return __uint_as_float(((unsigned)b) << 16);
}
// pack two f32 -> two bf16 (round-half-up): 2 adds + 1 perm  [proven]
__device__ inline unsigned pk2bf(float lo, float hi) {
    unsigned ul = __float_as_uint(lo) + 0x8000u;
    unsigned uh = __float_as_uint(hi) + 0x8000u;
    return __builtin_amdgcn_perm(uh, ul, 0x07060302u);
}

// [proven exp2 path]
#if __has_builtin(__builtin_amdgcn_exp2f)
#define EXP2F(x) __builtin_amdgcn_exp2f(x)
#else
#define EXP2F(x) exp2f(x)
#endif

// 16x16x16 bf16 MFMA
#if __has_builtin(__builtin_amdgcn_mfma_f32_16x16x16bf16_1k)
__device__ inline float4v mfma16(short4v a, short4v b, float4v c) {
    return __builtin_amdgcn_mfma_f32_16x16x16bf16_1k(a, b, c, 0, 0, 0);
}
#elif __has_builtin(__builtin_amdgcn_mfma_f32_16x16x16_bf16)
__device__ inline float4v mfma16(short4v a, short4v b, float4v c) {
    return __builtin_amdgcn_mfma_f32_16x16x16_bf16(a, b, c, 0, 0, 0);
}
#else
__device__ inline float4v mfma16(short4v a, short4v b, float4v c) {
    asm volatile("v_mfma_f32_16x16x16_bf16 %0, %1, %2, %0\n\ts_nop 4"
                 : "+v"(c) : "v"(a), "v"(b));
    return c;
}
#endif

#define GLDS16(gp, lp) __builtin_amdgcn_global_load_lds( \
    (const __attribute__((address_space(1))) void*)(gp), \
    (__attribute__((address_space(3))) void*)(lp), 16, 0, 0)

// ---------------------------------------------------------------------------
// prep: x cast | qkv_w cast (q/k rows permuted for in-register RoPE) |
// proj_w cast | packed cos/sin table   [identical to R6]
// ---------------------------------------------------------------------------
__global__ __launch_bounds__(256) void prep_all(
    const float* __restrict__ x, const float* __restrict__ qkv_w,
    const float* __restrict__ proj_w,
    const float* __restrict__ cos_t, const float* __restrict__ sin_t,
    unsigned short* __restrict__ xb, unsigned short* __restrict__ qkvwb,
    unsigned short* __restrict__ projwb, unsigned* __restrict__ csP)
{
    const int bid = blockIdx.x;
    if (bid < 8192) {
        int i = bid * 256 + threadIdx.x;
        float4 f = ((const float4*)x)[i];
        ushort4 o;
        o.x = f2bf(f.x); o.y = f2bf(f.y); o.z = f2bf(f.z); o.w = f2bf(f.w);
        ((ushort4*)xb)[i] = o;
    } else if (bid < 8192 + 3072) {
        const int rn = bid - 8192;
        int ro = rn;
        if (rn < 2048) {
            const int head = rn >> 6, c = rn & 63, j = c >> 4, cl = c & 15;
            ro = (head << 6) + ((j & 1) + 2 * cl + 32 * (j >> 1));
        }
        float4 f = ((const float4*)(qkv_w + (long)ro * DIM))[threadIdx.x];
        ushort4 o;
        o.x = f2bf(f.x); o.y = f2bf(f.y); o.z = f2bf(f.z); o.w = f2bf(f.w);
        ((ushort4*)(qkvwb + (long)rn * DIM))[threadIdx.x] = o;
    } else if (bid < 8192 + 3072 + 1024) {
        int i = (bid - 11264) * 256 + threadIdx.x;
        float4 f = ((const float4*)proj_w)[i];
        ushort4 o;
        o.x = f2bf(f.x); o.y = f2bf(f.y); o.z = f2bf(f.z); o.w = f2bf(f.w);
        ((ushort4*)projwb)[i] = o;
    } else {
        int i = (bid - 12288) * 256 + threadIdx.x;
        int a = i >> 11, s = i & 2047;
        float c = cos_t[s * 64 + 2 * a], sn = sin_t[s * 64 + 2 * a];
        csP[a * SEQ + s] = ((unsigned)f2bf(sn) << 16) | f2bf(c);
    }
}

// ---------------------------------------------------------------------------
// Fused QKV GEMM + bias + RMSNorm + RoPE + V fragment store  [identical to R6]
// ---------------------------------------------------------------------------
__global__ __launch_bounds__(256) void gemm_qkv_fused(
    const unsigned short* __restrict__ A, const unsigned short* __restrict__ W,
    const float* __restrict__ bias, const unsigned* __restrict__ csP,
    const float* __restrict__ qw, const float* __restrict__ kw,
    unsigned short* __restrict__ q, unsigned short* __restrict__ k,
    unsigned short* __restrict__ vt)
{
    __shared__ __align__(16) unsigned short As[128 * 32];
    __shared__ __align__(16) unsigned short Bs[128 * 32];

    const int t    = threadIdx.x;
    const int lane = t & 63;
    const int w    = t >> 6;
    const int row0 = blockIdx.y * 128;
    const int col0 = blockIdx.x * 128;
    const int wr   = (w & 1) * 64;
    const int wc   = (w >> 1) * 64;
    const int cl   = lane & 15;
    const int quad = lane >> 4;

    float4v acc[4][4];
#pragma unroll
    for (int i = 0; i < 4; ++i)
#pragma unroll
        for (int j = 0; j < 4; ++j) acc[i][j] = (float4v){0.f, 0.f, 0.f, 0.f};

    const int off1 = t * 16, off2 = 4096 + t * 16;
    const int r1 = off1 >> 6, c1 = off1 & 63;
    const int r2 = off2 >> 6, c2 = off2 & 63;
    const char* Ab = (const char*)A + (long)row0 * DIM * 2;
    const char* Wb = (const char*)W + (long)col0 * DIM * 2;
    const long  ks = DIM * 2;

    for (int k0 = 0; k0 < DIM; k0 += 32) {
        const long kb = (long)k0 * 2;
        GLDS16(Ab + (long)r1 * ks + kb + c1, (char*)As + off1);
        GLDS16(Ab + (long)r2 * ks + kb + c2, (char*)As + off2);
        GLDS16(Wb + (long)r1 * ks + kb + c1, (char*)Bs + off1);
        GLDS16(Wb + (long)r2 * ks + kb + c2, (char*)Bs + off2);
        __syncthreads();

        short8 af[4], bfr[4];
#pragma unroll
        for (int i = 0; i < 4; ++i)
            af[i] = *(const short8*)&As[(wr + i * 16 + cl) * 32 + quad * 8];
#pragma unroll
        for (int j = 0; j < 4; ++j)
            bfr[j] = *(const short8*)&Bs[(wc + j * 16 + cl) * 32 + quad * 8];
#pragma unroll
        for (int i = 0; i < 4; ++i)
#pragma unroll
            for (int j = 0; j < 4; ++j)
                acc[i][j] = __builtin_amdgcn_mfma_f32_16x16x32_bf16(af[i], bfr[j], acc[i][j], 0, 0, 0);
        __syncthreads();
    }

    const int gcol  = col0 + wc;
    const int b     = row0 >> 11;
    const int srow0 = (row0 & 2047) + wr;

    if (gcol < 2 * DIM) {
        const bool isq = (gcol < DIM);
        const int  h   = (isq ? gcol : gcol - DIM) >> 6;
        const float* nw = isq ? qw : kw;
        const float scale = isq ? 0.180336880f : 1.0f;   // 0.125*log2(e)
        unsigned short* dst = (isq ? q : k) + (long)(b * NH + h) * SEQ * 64;

        float bjv[4];
#pragma unroll
        for (int j = 0; j < 4; ++j)
            bjv[j] = bias[gcol + (j & 1) + 2 * cl + 32 * (j >> 1)];
#pragma unroll
        for (int i = 0; i < 4; ++i)
#pragma unroll
            for (int j = 0; j < 4; ++j)
#pragma unroll
                for (int r = 0; r < 4; ++r) acc[i][j][r] += bjv[j];

        float rinv[4][4];
#pragma unroll
        for (int i = 0; i < 4; ++i)
#pragma unroll
            for (int r = 0; r < 4; ++r) {
                float ss = acc[i][0][r] * acc[i][0][r];
                ss = fmaf(acc[i][1][r], acc[i][1][r], ss);
                ss = fmaf(acc[i][2][r], acc[i][2][r], ss);
                ss = fmaf(acc[i][3][r], acc[i][3][r], ss);
                ss += __shfl_xor(ss, 1, 64);
                ss += __shfl_xor(ss, 2, 64);
                ss += __shfl_xor(ss, 4, 64);
                ss += __shfl_xor(ss, 8, 64);
                rinv[i][r] = rsqrtf(ss * (1.f / 64.f) + EPS) * scale;
            }

        const float nwe[2] = { nw[2 * cl],     nw[32 + 2 * cl] };
        const float nwo[2] = { nw[2 * cl + 1], nw[33 + 2 * cl] };

#pragma unroll
        for (int i = 0; i < 4; ++i) {
            const int sb = srow0 + i * 16 + quad * 4;
#pragma unroll
            for (int jp = 0; jp < 2; ++jp) {
                uint4 cs4 = *(const uint4*)(csP + (long)(jp * 16 + cl) * SEQ + sb);
#pragma unroll
                for (int r = 0; r < 4; ++r) {
                    float g  = rinv[i][r];
                    float xe = acc[i][2 * jp][r]     * g * nwe[jp];
                    float xo = acc[i][2 * jp + 1][r] * g * nwo[jp];
                    unsigned u = (r == 0) ? cs4.x : (r == 1) ? cs4.y : (r == 2) ? cs4.z : cs4.w;
                    float c  = bf2f((unsigned short)(u & 0xffff));
                    float sn = bf2f((unsigned short)(u >> 16));
                    float oe = fmaf(xe, c, -(xo * sn));
                    float oo = fmaf(xo, c,   xe * sn);
                    *(unsigned*)(dst + (long)(sb + r) * 64 + jp * 32 + 2 * cl) = pk2bf(oe, oo);
                }
            }
        }
    } else {
        const int h = (gcol - 2 * DIM) >> 6;
        float bjv[4];
#pragma unroll
        for (int j = 0; j < 4; ++j) bjv[j] = bias[gcol + j * 16 + cl];
        unsigned short* vdst = vt + (long)(b * NH + h) * SEQ * 64
                                  + (long)(srow0 >> 6) * 4096;
#pragma unroll
        for (int j = 0; j < 4; ++j)
#pragma unroll
            for (int ip = 0; ip < 2; ++ip) {
                const int i0 = 2 * ip;
                uint4 st;
                st.x = pk2bf(acc[i0][j][0] + bjv[j],     acc[i0][j][1] + bjv[j]);
                st.y = pk2bf(acc[i0][j][2] + bjv[j],     acc[i0][j][3] + bjv[j]);
                st.z = pk2bf(acc[i0 + 1][j][0] + bjv[j], acc[i0 + 1][j][1] + bjv[j]);
                st.w = pk2bf(acc[i0 + 1][j][2] + bjv[j], acc[i0 + 1][j][3] + bjv[j]);
                *(uint4*)(vdst + (j * 2 + ip) * 512 + lane * 8) = st;
            }
    }
}

// ---------------------------------------------------------------------------
// proj GEMM  [identical to R6]
// ---------------------------------------------------------------------------
__global__ __launch_bounds__(256) void gemm_proj(
    const unsigned short* __restrict__ A, const unsigned short* __restrict__ W,
    const float* __restrict__ bias, float* __restrict__ C)
{
    __shared__ __align__(16) unsigned short As[128 * 32];
    __shared__ __align__(16) unsigned short Bs[128 * 32];

    const int t    = threadIdx.x;
    const int lane = t & 63;
    const int w    = t >> 6;
    const int row0 = blockIdx.y * 128;
    const int col0 = blockIdx.x * 128;
    const int wr   = (w & 1) * 64;
    const int wc   = (w >> 1) * 64;

    float4v acc[4][4];
#pragma unroll
    for (int i = 0; i < 4; ++i)
#pragma unroll
        for (int j = 0; j < 4; ++j) acc[i][j] = (float4v){0.f, 0.f, 0.f, 0.f};

    const int off1 = t * 16, off2 = 4096 + t * 16;
    const int r1 = off1 >> 6, c1 = off1 & 63;
    const int r2 = off2 >> 6, c2 = off2 & 63;
    const char* Ab = (const char*)A + (long)row0 * DIM * 2;
    const char* Wb = (const char*)W + (long)col0 * DIM * 2;
    const long  ks = DIM * 2;

    for (int k0 = 0; k0 < DIM; k0 += 32) {
        const long kb = (long)k0 * 2;
        GLDS16(Ab + (long)r1 * ks + kb + c1, (char*)As + off1);
        GLDS16(Ab + (long)r2 * ks + kb + c2, (char*)As + off2);
        GLDS16(Wb + (long)r1 * ks + kb + c1, (char*)Bs + off1);
        GLDS16(Wb + (long)r2 * ks + kb + c2, (char*)Bs + off2);
        __syncthreads();

        short8 af[4], bfr[4];
#pragma unroll
        for (int i = 0; i < 4; ++i)
            af[i] = *(const short8*)&As[(wr + i * 16 + (lane & 15)) * 32 + (lane >> 4) * 8];
#pragma unroll
        for (int j = 0; j < 4; ++j)
            bfr[j] = *(const short8*)&Bs[(wc + j * 16 + (lane & 15)) * 32 + (lane >> 4) * 8];
#pragma unroll
        for (int i = 0; i < 4; ++i)
#pragma unroll
            for (int j = 0; j < 4; ++j)
                acc[i][j] = __builtin_amdgcn_mfma_f32_16x16x32_bf16(af[i], bfr[j], acc[i][j], 0, 0, 0);
        __syncthreads();
    }

    const int qd = lane >> 4, cl = lane & 15;
#pragma unroll
    for (int j = 0; j < 4; ++j) {
        const int col = col0 + wc + j * 16 + cl;
        const float bj = bias[col];
#pragma unroll
        for (int i = 0; i < 4; ++i) {
            const long rr = row0 + wr + i * 16 + qd * 4;
#pragma unroll
            for (int r = 0; r < 4; ++r)
                C[(rr + r) * (long)DIM + col] = acc[i][j][r] + bj;
        }
    }
}

// ---------------------------------------------------------------------------
// MFMA flash attention. R3-R5 nulls (conflicts->0, fewer barriers, fewer
// drained bytes) localize the stall to K-ARRIVAL SERIALIZATION: each
// iteration issues K staging then immediately drains it (vmcnt(0) inside
// __syncthreads), exposing L2/HBM latency every iteration. Fix (T14
// issue-early/wait-late, minimal form):
//   1. pull K frags LDS->reg (8x ds_read_b128), lgkmcnt(0), RAW s_barrier
//   2. issue K(kt+1) global_load_lds into the SAME 8KB buffer
//   3. V loads + QK + softmax + PV (~2000cy) cover the K HBM latency
//   4. s_waitcnt vmcnt(0) (waits on loads issued a compute-phase ago ->
//      nearly free) + RAW s_barrier
// Raw barriers + hand waitcnts keep the prefetch in flight across the
// barrier (R2 failed because __syncthreads' implicit vmcnt(0) drained it).
// Single buffer: no LDS growth, no runtime-indexed bases. sched_barrier(0)
// fences per guide rule #18; "memory" clobbers pin the ds_reads.
// ---------------------------------------------------------------------------
__global__ __launch_bounds__(256, 4) void flash_mfma(
    const unsigned short* __restrict__ q, const unsigned short* __restrict__ k,
    const unsigned short* __restrict__ vt, unsigned short* __restrict__ out)
{
    __shared__ __align__(16) unsigned short Ks[2][64 * 32];

    const int t    = threadIdx.x;
    const int lane = t & 63;
    const int w    = t >> 6;
    const int bh   = blockIdx.y;
    const int b    = bh >> 4;
    const int h    = bh & 15;
    const int q0   = blockIdx.x * 128;
    const int cl   = lane & 15;
    const int quad = lane >> 4;
    // swizzled 16B slot for K reads: row = j*16+cl, (row>>1)&3 == (cl>>1)&3
    const int qs   = quad ^ ((cl >> 1) & 3);

    const char* qb  = (const char*)(q  + (long)bh * SEQ * 64);
    const char* kb  = (const char*)(k  + (long)bh * SEQ * 64);
    const char* vtb = (const char*)(vt + (long)bh * SEQ * 64);

    // Q fragments straight to registers (read once, outside the loop)
    short8 aq[2][2];
#pragma unroll
    for (int qg = 0; qg < 2; ++qg)
#pragma unroll
        for (int hf = 0; hf < 2; ++hf)
            aq[qg][hf] = *(const short8*)(qb +
                (long)(q0 + w * 32 + qg * 16 + cl) * 128 + hf * 64 + quad * 16);

    const short4v ones = (short4v){(short)0x3F80, (short)0x3F80,
                                   (short)0x3F80, (short)0x3F80};

    float4v o[2][4], o4[2];
#pragma unroll
    for (int qg = 0; qg < 2; ++qg) {
        o4[qg] = (float4v){0.f, 0.f, 0.f, 0.f};
#pragma unroll
        for (int i = 0; i < 4; ++i) o[qg][i] = (float4v){0.f, 0.f, 0.f, 0.f};
    }

    const int soff = t * 16, srow = soff >> 6;
    // source column pre-swizzled with the SAME involution the read applies:
    // LDS(row, c) = G(row, c ^ f(row)),  f(row) = ((row>>1)&3)<<4
    const int scbS = (soff & 63) ^ (((srow >> 1) & 3) << 4);

    const int NT = SEQ / 64;

    // prologue: stage tile 0 and wait for it
    GLDS16(kb + (long)srow * 128 + scbS,      (char*)Ks[0] + soff);
    GLDS16(kb + (long)srow * 128 + 64 + scbS, (char*)Ks[1] + soff);
    asm volatile("s_waitcnt vmcnt(0)" ::: "memory");
    __builtin_amdgcn_s_barrier();
    __builtin_amdgcn_sched_barrier(0);

    for (int kt = 0; kt < NT; ++kt) {
        // (1) pull this tile's K fragments into registers
        short8 ka0[4], ka1[4];
#pragma unroll
        for (int j = 0; j < 4; ++j) {
            ka0[j] = *(const short8*)&Ks[0][(j * 16 + cl) * 32 + qs * 8];
            ka1[j] = *(const short8*)&Ks[1][(j * 16 + cl) * 32 + qs * 8];
        }
        asm volatile("s_waitcnt lgkmcnt(0)" ::: "memory");
        __builtin_amdgcn_s_barrier();          // all waves done reading Ks
        __builtin_amdgcn_sched_barrier(0);

        // (2) prefetch next K tile into the SAME buffer; lands under compute
        if (kt + 1 < NT) {
            const long grow = (long)((kt + 1) * 64 + srow) * 128;
            GLDS16(kb + grow + scbS,      (char*)Ks[0] + soff);
            GLDS16(kb + grow + 64 + scbS, (char*)Ks[1] + soff);
        }

        // (3) V fragments direct global->reg; latency under QK+softmax
        short8 vf[8];
#pragma unroll
        for (int m = 0; m < 8; ++m)
            vf[m] = *(const short8*)(vtb + (long)kt * 8192 + m * 1024 + lane * 16);

        // (4) QK + softmax (+ row sums on the MFMA pipe)
        short4v pa[2][4];
#pragma unroll
        for (int j = 0; j < 4; ++j) {
#pragma unroll
            for (int qg = 0; qg < 2; ++qg) {
                float4v z = (float4v){0.f, 0.f, 0.f, 0.f};
                z = __builtin_amdgcn_mfma_f32_16x16x32_bf16(ka0[j], aq[qg][0], z, 0, 0, 0);
                float4v s = __builtin_amdgcn_mfma_f32_16x16x32_bf16(ka1[j], aq[qg][1], z, 0, 0, 0);
                float p0 = EXP2F(s[0]), p1 = EXP2F(s[1]);
                float p2 = EXP2F(s[2]), p3 = EXP2F(s[3]);
                unsigned lo = pk2bf(p0, p1), hi = pk2bf(p2, p3);
                pa[qg][j] = __builtin_bit_cast(short4v, ((unsigned long long)hi << 32) | lo);
                o4[qg] = mfma16(ones, pa[qg][j], o4[qg]);
            }
        }

        // (5) O^T += V^T @ P^T (V fragments in registers)
#pragma unroll
        for (int fi = 0; fi < 4; ++fi) {
#pragma unroll
            for (int fjp = 0; fjp < 2; ++fjp) {
                short8 vv = vf[fi * 2 + fjp];
                short4v va = __builtin_shufflevector(vv, vv, 0, 1, 2, 3);
                short4v vb = __builtin_shufflevector(vv, vv, 4, 5, 6, 7);
#pragma unroll
                for (int qg = 0; qg < 2; ++qg) {
                    o[qg][fi] = mfma16(va, pa[qg][2 * fjp],     o[qg][fi]);
                    o[qg][fi] = mfma16(vb, pa[qg][2 * fjp + 1], o[qg][fi]);
                }
            }
        }

        // (6) own prefetch landed (issued a compute-phase ago -> cheap),
        //     then all-waves sync so everyone's K(kt+1) is in LDS
        asm volatile("s_waitcnt vmcnt(0)" ::: "memory");
        __builtin_amdgcn_s_barrier();
        __builtin_amdgcn_sched_barrier(0);
    }

#pragma unroll
    for (int qg = 0; qg < 2; ++qg) {
        const float inv = 1.f / o4[qg][0];
        unsigned short* orow = out + ((long)b * SEQ + q0 + w * 32 + qg * 16 + cl) * DIM + h * 64;
#pragma unroll
        for (int i = 0; i < 4; ++i) {
            unsigned lo = pk2bf(o[qg][i][0] * inv, o[qg][i][1] * inv);
            unsigned hi = pk2bf(o[qg][i][2] * inv, o[qg][i][3] * inv);
            ushort4 st = __builtin_bit_cast(ushort4, ((unsigned long long)hi << 32) | lo);
            *(ushort4*)(orow + i * 16 + quad * 4) = st;
        }
    }
}

// ---------------------------------------------------------------------------
extern "C" void kernel_launch(void* const* d_in, const int* in_sizes, int n_in,
                              void* d_out, int out_size, void* d_ws, size_t ws_size,
                              hipStream_t stream)
{
    const float* x        = (const float*)d_in[0];
    const float* rope_cos = (const float*)d_in[1];
    const float* rope_sin = (const float*)d_in[2];
    const float* qkv_w    = (const float*)d_in[3];
    const float* qkv_b    = (const float*)d_in[4];
    const float* proj_w   = (const float*)d_in[5];
    const float* proj_b   = (const float*)d_in[6];
    const float* q_norm_w = (const float*)d_in[7];
    const float* k_norm_w = (const float*)d_in[8];
    float* outp = (float*)d_out;

    const int M = BATCH * SEQ;
    char* p = (char*)d_ws;
    unsigned short* xb    = (unsigned short*)p; p += (long)M * DIM * 2;
    unsigned short* qkvwb = (unsigned short*)p; p += (long)3 * DIM * DIM * 2;
    unsigned short* projwb= (unsigned short*)p; p += (long)DIM * DIM * 2;
    unsigned short* qb    = (unsigned short*)p; p += (long)M * DIM * 2;
    unsigned short* kbuf  = (unsigned short*)p; p += (long)M * DIM * 2;
    unsigned short* vtb   = (unsigned short*)p; p += (long)M * DIM * 2;
    unsigned short* attno = (unsigned short*)p; p += (long)M * DIM * 2;
    unsigned*       csP   = (unsigned*)p;       p += (long)32 * SEQ * 4;

    prep_all<<<dim3(12544), 256, 0, stream>>>(
        x, qkv_w, proj_w, rope_cos, rope_sin, xb, qkvwb, projwb, csP);

    gemm_qkv_fused<<<dim3(3 * DIM / 128, M / 128), 256, 0, stream>>>(
        xb, qkvwb, qkv_b, csP, q_norm_w, k_norm_w, qb, kbuf, vtb);

    flash_mfma<<<dim3(SEQ / 128, BATCH * NH), 256, 0, stream>>>(qb, kbuf, vtb, attno);

    gemm_proj<<<dim3(DIM / 128, M / 128), 256, 0, stream>>>(
        attno, projwb, proj_b, outp);
}